// Round 8
// baseline (1133.436 us; speedup 1.0000x reference)
//
#include <hip/hip_runtime.h>

#define BB 16
#define NN 1536
#define FF 128
#define SLOPE 0.2f
#define TI 16
#define JC 64
#define NPB (NN/8)   // 192 k_par blocks per sample

// ---- per-sample active-node compaction (ordered), cnt ----
__global__ __launch_bounds__(256) void k_compact(const int* __restrict__ data,
    int* __restrict__ act, int* __restrict__ cnt)
{
  int b = blockIdx.x, t = threadIdx.x;
  const int PER = NN/256;                 // 6
  int local[NN/256]; int nl = 0;
  int base = t*PER;
  #pragma unroll
  for (int u=0; u<PER; ++u){
    if (data[b*NN + base + u] != 0) local[nl++] = base+u;
  }
  __shared__ int s[256];
  s[t]=nl; __syncthreads();
  if (t==0){ int run=0; for (int i=0;i<256;i++){ int v=s[i]; s[i]=run; run+=v; } cnt[b]=run; }
  __syncthreads();
  int o = s[t];
  for (int u=0; u<nl; ++u) act[b*NN + o + u] = local[u];
}

// ---- h_N = embed[-1] @ dec_W, si_N, sj_N (sample-independent) ----
__global__ __launch_bounds__(128) void k_hn(const float* __restrict__ embed,
    const float* __restrict__ decW, const float* __restrict__ aS, const float* __restrict__ aD,
    float* __restrict__ hN, float* __restrict__ sN)
{
  int f = threadIdx.x;
  float acc = 0.f;
  for (int k=0;k<FF;++k) acc += embed[(long)NN*FF + k] * decW[k*FF + f];
  hN[f] = acc;
  float ps = acc * aS[f];
  float pd = acc * aD[f];
  #pragma unroll
  for (int o=32;o;o>>=1){ ps += __shfl_down(ps,o); pd += __shfl_down(pd,o); }
  __shared__ float rs[2][2];
  if ((f&63)==0){ rs[0][f>>6]=ps; rs[1][f>>6]=pd; }
  __syncthreads();
  if (f==0){ sN[0]=rs[0][0]+rs[0][1]; sN[1]=rs[1][0]+rs[1][1]; }
}

// ---- generic row-matmul: H = X @ W (F x F), SI = H@aSrc, SJ = H@aDst ----
__global__ __launch_bounds__(128) void k_rowmm(const float* __restrict__ Xv, long xStride,
    const float* __restrict__ W, const float* __restrict__ aS, const float* __restrict__ aD,
    float* __restrict__ Hb, float* __restrict__ SIb, float* __restrict__ SJb,
    const int* __restrict__ cntArr)
{
  int b = blockIdx.y;
  int cnt = cntArr ? cntArr[b] : NN;
  int r0 = blockIdx.x*8;
  if (r0 >= cnt) return;
  int f = threadIdx.x;
  float* H  = Hb  + (long)b*NN*FF;
  float* SI = SIb + (long)b*NN;
  float* SJ = SJb + (long)b*NN;
  __shared__ float xs[8][FF];
  #pragma unroll
  for (int r=0;r<8;++r){
    int rr=r0+r; float v=0.f;
    if (rr<cnt) v = Xv[(long)b*xStride + (long)rr*FF + f];
    xs[r][f]=v;
  }
  __syncthreads();
  float acc[8]={0.f,0.f,0.f,0.f,0.f,0.f,0.f,0.f};
  for (int k=0;k<FF;++k){
    float w = W[k*FF + f];
    #pragma unroll
    for (int r=0;r<8;++r) acc[r] += xs[r][k]*w;
  }
  float as = aS[f], ad = aD[f];
  __shared__ float red[2][8][2];
  #pragma unroll
  for (int r=0;r<8;++r){
    int rr=r0+r;
    if (rr<cnt) H[(long)rr*FF + f] = acc[r];
    float ps = acc[r]*as, pd = acc[r]*ad;
    #pragma unroll
    for (int o=32;o;o>>=1){ ps += __shfl_down(ps,o); pd += __shfl_down(pd,o); }
    if ((f&63)==0){ red[0][r][f>>6]=ps; red[1][r][f>>6]=pd; }
  }
  __syncthreads();
  if (f<8){
    int rr=r0+f;
    if (rr<cnt){ SI[rr]=red[0][f][0]+red[0][f][1]; SJ[rr]=red[1][f][0]+red[1][f][1]; }
  }
}

// ---- dense GAT aggregation (flash-style tiles), writes elu(out) compacted ----
__global__ __launch_bounds__(128) void k_agg_dense(
    const float* __restrict__ SJb, const float* __restrict__ SIb,
    const int* __restrict__ actB,
    const float* __restrict__ Hb, long hStride, long sStride,
    const int* __restrict__ cntArr, float* __restrict__ XoB)
{
  int b = blockIdx.y;
  int cnt = cntArr[b];
  int r0 = blockIdx.x*TI;
  if (r0 >= cnt) return;
  int f = threadIdx.x; // 0..127
  const float* SJ = SJb + (long)b*sStride;
  const float* SI = SIb + (long)b*sStride;
  const int* act = actB ? actB + b*NN : nullptr;
  const float* H = Hb + (long)b*hStride;
  float* xo = XoB + (long)b*NN*FF;

  __shared__ float hs[JC][FF];
  __shared__ float sjs[JC];
  __shared__ float wt[TI][JC];
  __shared__ float sis[TI];

  if (f < TI){
    int rr = r0 + f;
    float si = 0.f;
    if (rr < cnt){ int i = act ? act[rr] : rr; si = SI[i]; }
    sis[f] = si;
  }
  __syncthreads();

  float acc[TI], accW[TI];
  #pragma unroll
  for (int r=0;r<TI;++r){ acc[r]=0.f; accW[r]=0.f; }

  for (int j0=0; j0<cnt; j0+=JC){
    int jn = cnt - j0; if (jn > JC) jn = JC;
    for (int e=f; e<JC*FF; e+=128){
      int jj=e>>7, ff=e&127;
      float v=0.f;
      if (jj<jn){ int j = act ? act[j0+jj] : (j0+jj); v = H[(long)j*FF + ff]; }
      hs[jj][ff]=v;
    }
    if (f<JC){
      float sj=0.f;
      if (f<jn){ int j = act ? act[j0+f] : (j0+f); sj = SJ[j]; }
      sjs[f]=sj;
    }
    __syncthreads();
    for (int e=f; e<TI*JC; e+=128){
      int rr=e/JC, jj=e-rr*JC;
      float w=0.f;
      if (jj<jn && (r0+rr)<cnt){
        float x = sis[rr]+sjs[jj];
        float ee = (x>=0.f)? x : SLOPE*x;
        w = __expf(ee);
      }
      wt[rr][jj]=w;
    }
    __syncthreads();
    for (int jj=0;jj<jn;++jj){
      float hv = hs[jj][f];
      #pragma unroll
      for (int r=0;r<TI;++r){
        float w = wt[r][jj];
        acc[r] += w*hv;
        accW[r] += w;
      }
    }
    __syncthreads();
  }
  #pragma unroll
  for (int r=0;r<TI;++r){
    int rr=r0+r;
    if (rr<cnt){
      float o2 = acc[r]/accW[r];
      xo[(long)rr*FF + f] = (o2>0.f)? o2 : (__expf(o2)-1.f);
    }
  }
}

// ---- par = x2 @ param_W + b; store mean; write per-block kld partial ----
__global__ __launch_bounds__(256) void k_par(const float* __restrict__ XC,
    const float* __restrict__ pW, const float* __restrict__ pB,
    float* __restrict__ MEAN, float* __restrict__ KPART, const int* __restrict__ cntArr)
{
  int b = blockIdx.y; int cnt = cntArr[b];
  int bx = blockIdx.x;
  int r0 = bx*8;
  int t = threadIdx.x;
  if (r0>=cnt){
    if (t==0) KPART[b*NPB + bx] = 0.f;
    return;
  }
  const float* X = XC + (long)b*NN*FF;
  __shared__ float xs[8][FF];
  for (int e=t; e<8*FF; e+=256){
    int r=e>>7, k=e&127; int rr=r0+r;
    xs[r][k] = (rr<cnt) ? X[(long)rr*FF+k] : 0.f;
  }
  __syncthreads();
  float acc[8]={0.f,0.f,0.f,0.f,0.f,0.f,0.f,0.f};
  for (int k=0;k<FF;++k){
    float w = pW[k*2*FF + t];
    #pragma unroll
    for (int r=0;r<8;++r) acc[r]+=xs[r][k]*w;
  }
  float bb = pB[t];
  float kacc=0.f;
  #pragma unroll
  for (int r=0;r<8;++r){
    int rr=r0+r;
    if (rr>=cnt) continue;
    float v = acc[r]+bb;
    if (t<FF){ MEAN[(long)b*NN*FF + (long)rr*FF + t]=v; kacc += v*v; }
    else kacc += __expf(v)-v-1.f;
  }
  #pragma unroll
  for (int o=32;o;o>>=1) kacc += __shfl_down(kacc,o);
  __shared__ float rw[4];
  if ((t&63)==0) rw[t>>6]=kacc;
  __syncthreads();
  if (t==0) KPART[b*NPB + bx] = rw[0]+rw[1]+rw[2]+rw[3];
}

// ---- decoder partial reduction: sum_j w_j*h3_j over chunk ----
__global__ __launch_bounds__(128) void k_dec(const float* __restrict__ H3,
    const float* __restrict__ SJ3, const float* __restrict__ sN,
    const int* __restrict__ cntArr, float* __restrict__ DECP)
{
  int b=blockIdx.y, ch=blockIdx.x;
  int cnt=cntArr[b];
  int f=threadIdx.x;
  int r0=ch*96; int r1 = (r0+96 < cnt) ? r0+96 : cnt;
  float siN = sN[0];
  const float* H = H3 + (long)b*NN*FF;
  const float* SJ = SJ3 + (long)b*NN;
  float accV=0.f, accW=0.f;
  for (int r=r0;r<r1;++r){
    float sj=SJ[r]; float x=siN+sj;
    float e=(x>=0.f)? x : SLOPE*x;
    float w=__expf(e);
    accV += w*H[(long)r*FF+f];
    accW += w;
  }
  float* P = DECP + (long)(b*16+ch)*(FF+1);
  P[f]=accV;
  if (f==0) P[FF]=accW;
}

// ---- final: feats -> MLP head -> pred (fp32); kld reduced from partials ----
__global__ __launch_bounds__(128) void k_final(const float* __restrict__ DECP,
    const float* __restrict__ hN, const float* __restrict__ sN,
    const float* __restrict__ KPART, const int* __restrict__ cntArr,
    const float* __restrict__ W1, const float* __restrict__ b1,
    const float* __restrict__ W2, const float* __restrict__ b2,
    float* __restrict__ out)   // FP32 output (reference computes in float32)
{
  int f=threadIdx.x;
  __shared__ float feats[BB][FF];
  float siN=sN[0], sjN=sN[1];
  float xN=siN+sjN; float eN=(xN>=0.f)?xN:SLOPE*xN; float wN=__expf(eN);
  for (int b=0;b<BB;++b){
    float num=0.f, den=0.f;
    for (int c=0;c<16;++c){
      const float* P = DECP + (long)(b*16+c)*(FF+1);
      num += P[f]; den += P[FF];
    }
    num += wN*hN[f]; den += wN;
    float v=num/den;
    feats[b][f] = (v>0.f)? v : 0.f;
  }
  __syncthreads();
  __shared__ float rw[2];
  for (int b=0;b<BB;++b){
    float acc=0.f;
    for (int k=0;k<FF;++k) acc += feats[b][k]*W1[k*FF+f];
    acc += b1[f];
    acc = (acc>0.f)? acc : 0.f;
    float p = acc*W2[f];
    #pragma unroll
    for (int o=32;o;o>>=1) p += __shfl_down(p,o);
    if ((f&63)==0) rw[f>>6]=p;
    __syncthreads();
    if (f==0) out[b] = rw[0]+rw[1]+b2[0];
    __syncthreads();
  }
  // kld: reduce 192 partials per sample, scale by 0.5/cnt, sum over samples
  float s=0.f;
  for (int b=0;b<BB;++b){
    float part=0.f;
    for (int c=f;c<NPB;c+=128) part += KPART[b*NPB + c];
    #pragma unroll
    for (int o=32;o;o>>=1) part += __shfl_down(part,o);
    if ((f&63)==0) rw[f>>6]=part;
    __syncthreads();
    float tot = rw[0]+rw[1];
    int c=cntArr[b]; float cf = (c>0)? (float)c : 1.f;
    s += 0.5f*tot/cf;
    __syncthreads();
  }
  if (f==0) out[16]=s;
}

extern "C" void kernel_launch(void* const* d_in, const int* in_sizes, int n_in,
                              void* d_out, int out_size, void* d_ws, size_t ws_size,
                              hipStream_t stream)
{
  const int*   data  = (const int*)d_in[0];
  const float* embed = (const float*)d_in[1];
  const float* encW  = (const float*)d_in[2];
  const float* encAs = (const float*)d_in[3];
  const float* encAd = (const float*)d_in[4];
  const float* pW    = (const float*)d_in[5];
  const float* pB    = (const float*)d_in[6];
  const float* decW  = (const float*)d_in[7];
  const float* decAs = (const float*)d_in[8];
  const float* decAd = (const float*)d_in[9];
  const float* oW1   = (const float*)d_in[10];
  const float* oB1   = (const float*)d_in[11];
  const float* oW2   = (const float*)d_in[12];
  const float* oB2   = (const float*)d_in[13];
  float* out = (float*)d_out;   // float32 output

  float* w = (float*)d_ws;
  long o = 0;
  float* H1   = w+o; o += (long)NN*FF;
  float* H2   = w+o; o += (long)BB*NN*FF;   // later reused as MEAN
  float* XC   = w+o; o += (long)BB*NN*FF;   // layer outputs; later reused as H3
  float* SI1  = w+o; o += NN;
  float* SJ1  = w+o; o += NN;
  float* SI2  = w+o; o += (long)BB*NN;
  float* SJ2  = w+o; o += (long)BB*NN;
  float* KPART= w+o; o += (long)BB*NPB;
  float* hN   = w+o; o += FF;
  float* sN   = w+o; o += 2;
  float* DECP = w+o; o += (long)BB*16*(FF+1);
  int* act = (int*)(w+o); o += (long)BB*NN;
  int* cnt = (int*)(w+o); o += BB;
  (void)in_sizes; (void)n_in; (void)out_size; (void)ws_size;

  k_compact<<<BB,256,0,stream>>>(data, act, cnt);
  k_hn<<<1,128,0,stream>>>(embed, decW, decAs, decAd, hN, sN);
  // encoder layer 1 (shared h/si/sj across samples)
  k_rowmm<<<dim3(NN/8,1),128,0,stream>>>(embed, 0L,
      encW, encAs, encAd, H1, SI1, SJ1, nullptr);
  k_agg_dense<<<dim3(NN/TI,BB),128,0,stream>>>(SJ1, SI1, act, H1, 0L, 0L, cnt, XC);
  // encoder layer 2 (per-sample, compacted)
  k_rowmm<<<dim3(NN/8,BB),128,0,stream>>>(XC, (long)NN*FF,
      encW + FF*FF, encAs + FF, encAd + FF, H2, SI2, SJ2, cnt);
  k_agg_dense<<<dim3(NN/TI,BB),128,0,stream>>>(SJ2, SI2, nullptr, H2, (long)NN*FF, (long)NN, cnt, XC);
  // param head + kld partials (XC -> MEAN into H2)
  k_par<<<dim3(NPB,BB),256,0,stream>>>(XC, pW, pB, H2 /*MEAN*/, KPART, cnt);
  // decoder projection + scores (MEAN=H2 -> H3=XC)
  k_rowmm<<<dim3(NN/8,BB),128,0,stream>>>(H2 /*MEAN*/, (long)NN*FF,
      decW, decAs, decAd, XC /*H3*/, SI2, SJ2, cnt);
  k_dec<<<dim3(16,BB),128,0,stream>>>(XC /*H3*/, SJ2, sN, cnt, DECP);
  k_final<<<1,128,0,stream>>>(DECP, hN, sN, KPART, cnt, oW1, oB1, oW2, oB2, out);
}

// Round 9
// 1103.172 us; speedup vs baseline: 1.0274x; 1.0274x over previous
//
#include <hip/hip_runtime.h>

#define BB 16
#define NN 1536
#define FF 128
#define SLOPE 0.2f
#define NS 2048
#define NPB (NN/8)   // 192 k_par blocks per sample

// ---- per-sample active-node compaction (ordered), cnt ----
__global__ __launch_bounds__(256) void k_compact(const int* __restrict__ data,
    int* __restrict__ act, int* __restrict__ cnt)
{
  int b = blockIdx.x, t = threadIdx.x;
  const int PER = NN/256;                 // 6
  int local[NN/256]; int nl = 0;
  int base = t*PER;
  #pragma unroll
  for (int u=0; u<PER; ++u){
    if (data[b*NN + base + u] != 0) local[nl++] = base+u;
  }
  __shared__ int s[256];
  s[t]=nl; __syncthreads();
  if (t==0){ int run=0; for (int i=0;i<256;i++){ int v=s[i]; s[i]=run; run+=v; } cnt[b]=run; }
  __syncthreads();
  int o = s[t];
  for (int u=0; u<nl; ++u) act[b*NN + o + u] = local[u];
}

// ---- h_N = embed[-1] @ dec_W, si_N, sj_N (sample-independent) ----
__global__ __launch_bounds__(128) void k_hn(const float* __restrict__ embed,
    const float* __restrict__ decW, const float* __restrict__ aS, const float* __restrict__ aD,
    float* __restrict__ hN, float* __restrict__ sN)
{
  int f = threadIdx.x;
  float acc = 0.f;
  for (int k=0;k<FF;++k) acc += embed[(long)NN*FF + k] * decW[k*FF + f];
  hN[f] = acc;
  float ps = acc * aS[f];
  float pd = acc * aD[f];
  #pragma unroll
  for (int o=32;o;o>>=1){ ps += __shfl_down(ps,o); pd += __shfl_down(pd,o); }
  __shared__ float rs[2][2];
  if ((f&63)==0){ rs[0][f>>6]=ps; rs[1][f>>6]=pd; }
  __syncthreads();
  if (f==0){ sN[0]=rs[0][0]+rs[0][1]; sN[1]=rs[1][0]+rs[1][1]; }
}

// ---- generic row-matmul: H = X @ W (F x F), SI = H@aSrc, SJ = H@aDst ----
__global__ __launch_bounds__(128) void k_rowmm(const float* __restrict__ Xv, long xStride,
    const float* __restrict__ W, const float* __restrict__ aS, const float* __restrict__ aD,
    float* __restrict__ Hb, float* __restrict__ SIb, float* __restrict__ SJb,
    const int* __restrict__ cntArr)
{
  int b = blockIdx.y;
  int cnt = cntArr ? cntArr[b] : NN;
  int r0 = blockIdx.x*8;
  if (r0 >= cnt) return;
  int f = threadIdx.x;
  float* H  = Hb  + (long)b*NN*FF;
  float* SI = SIb + (long)b*NN;
  float* SJ = SJb + (long)b*NN;
  __shared__ float xs[8][FF];
  #pragma unroll
  for (int r=0;r<8;++r){
    int rr=r0+r; float v=0.f;
    if (rr<cnt) v = Xv[(long)b*xStride + (long)rr*FF + f];
    xs[r][f]=v;
  }
  __syncthreads();
  float acc[8]={0.f,0.f,0.f,0.f,0.f,0.f,0.f,0.f};
  for (int k=0;k<FF;++k){
    float w = W[k*FF + f];
    #pragma unroll
    for (int r=0;r<8;++r) acc[r] += xs[r][k]*w;
  }
  float as = aS[f], ad = aD[f];
  __shared__ float red[2][8][2];
  #pragma unroll
  for (int r=0;r<8;++r){
    int rr=r0+r;
    if (rr<cnt) H[(long)rr*FF + f] = acc[r];
    float ps = acc[r]*as, pd = acc[r]*ad;
    #pragma unroll
    for (int o=32;o;o>>=1){ ps += __shfl_down(ps,o); pd += __shfl_down(pd,o); }
    if ((f&63)==0){ red[0][r][f>>6]=ps; red[1][r][f>>6]=pd; }
  }
  __syncthreads();
  if (f<8){
    int rr=r0+f;
    if (rr<cnt){ SI[rr]=red[0][f][0]+red[0][f][1]; SJ[rr]=red[1][f][0]+red[1][f][1]; }
  }
}

// ---- separable GAT aggregation via dual sort + two-pointer sweep ----
// exp(lrelu(si+sj)) = e^si e^sj (si+sj>0) else e^.2si e^.2sj  ->  O(cnt*F).
// One block per sample, 256 threads (sweep on first 128: one feature/lane).
__global__ __launch_bounds__(256) void k_agg_sep(
    const float* __restrict__ SJb, const float* __restrict__ SIb,
    const int* __restrict__ actB,
    const float* __restrict__ Hb, long hStride, long sStride,
    const int* __restrict__ cntArr, float* __restrict__ XoB)
{
  int b = blockIdx.x;
  int cnt = cntArr[b];
  const float* SJ = SJb + (long)b*sStride;
  const float* SI = SIb + (long)b*sStride;
  const int* act = actB ? actB + b*NN : nullptr;
  const float* H = Hb + (long)b*hStride;
  float* xo = XoB + (long)b*NN*FF;
  int t = threadIdx.x;

  __shared__ float keyJ[NS]; __shared__ int pj[NS];   // sj asc; payload = H row idx
  __shared__ float keyI[NS]; __shared__ int pi[NS];   // -si asc; payload = compact row idx
  __shared__ float wb[NS], wd[NS];                    // e^sj, e^(0.2 sj) in sorted order
  __shared__ float TBv[2][FF];
  __shared__ float TBsh[2];

  int NSort = 32; while (NSort < cnt) NSort <<= 1;    // cnt <= 1536 -> <= 2048

  for (int e=t; e<NSort; e+=256){
    if (e<cnt){
      int io = act ? act[e] : e;
      keyJ[e]=SJ[io]; pj[e]=io;
      keyI[e]=-SI[io]; pi[e]=e;
    } else {
      keyJ[e]=__builtin_inff(); pj[e]=0;
      keyI[e]=__builtin_inff(); pi[e]=0;
    }
  }
  __syncthreads();

  // XOR-bitonic, both key arrays per pass (shared barriers)
  for (int k=2; k<=NSort; k<<=1){
    for (int j=k>>1; j>0; j>>=1){
      for (int e=t; e<NSort; e+=256){
        int l = e ^ j;
        if (l > e){
          bool asc = ((e & k) == 0);
          float a0=keyJ[e], a1=keyJ[l];
          if (asc ? (a0>a1) : (a0<a1)){
            keyJ[e]=a1; keyJ[l]=a0; int p=pj[e]; pj[e]=pj[l]; pj[l]=p;
          }
          float b0=keyI[e], b1=keyI[l];
          if (asc ? (b0>b1) : (b0<b1)){
            keyI[e]=b1; keyI[l]=b0; int p=pi[e]; pi[e]=pi[l]; pi[l]=p;
          }
        }
      }
      __syncthreads();
    }
  }

  // branch weights in sorted-j order
  for (int e=t; e<NSort; e+=256){
    float kk = (e<cnt) ? keyJ[e] : 0.f;
    wb[e]=__expf(kk); wd[e]=__expf(SLOPE*kk);
  }
  __syncthreads();

  // totals TB[f] = sum_j e^sj h_j[f], TBs = sum_j e^sj  (split across halves)
  {
    int half = t>>7, f = t&127;
    int k0 = half ? (cnt>>1) : 0;
    int k1 = half ? cnt : (cnt>>1);
    float tb=0.f, tbs=0.f;
    for (int k=k0;k<k1;++k){
      float hv = H[(long)pj[k]*FF + f];
      tb += wb[k]*hv; tbs += wb[k];
    }
    TBv[half][f]=tb;
    if (f==0) TBsh[half]=tbs;
  }
  __syncthreads();

  // two-pointer sweep: rows in si-descending order; prefix = {j: sj <= -si}
  if (t < 128){
    float TB  = TBv[0][t]+TBv[1][t];
    float TBs = TBsh[0]+TBsh[1];
    float accB=0.f, accD=0.f, accBs=0.f, accDs=0.f;
    int jp=0;
    for (int r=0;r<cnt;++r){
      float th = keyI[r];                      // = -si
      while (jp<cnt && keyJ[jp] <= th){
        float hv = H[(long)pj[jp]*FF + t];
        float wbv = wb[jp], wdv = wd[jp];
        accB  += wbv*hv;  accD  += wdv*hv;
        accBs += wbv;     accDs += wdv;
        ++jp;
      }
      float si = -th;
      float ai = __expf(si), ci = __expf(SLOPE*si);
      float num = ai*(TB -accB ) + ci*accD;
      float den = ai*(TBs-accBs) + ci*accDs;
      float o2 = num/den;
      xo[(long)pi[r]*FF + t] = (o2>0.f)? o2 : (__expf(o2)-1.f);
    }
  }
}

// ---- par = x2 @ param_W + b; store mean; write per-block kld partial ----
__global__ __launch_bounds__(256) void k_par(const float* __restrict__ XC,
    const float* __restrict__ pW, const float* __restrict__ pB,
    float* __restrict__ MEAN, float* __restrict__ KPART, const int* __restrict__ cntArr)
{
  int b = blockIdx.y; int cnt = cntArr[b];
  int bx = blockIdx.x;
  int r0 = bx*8;
  int t = threadIdx.x;
  if (r0>=cnt){
    if (t==0) KPART[b*NPB + bx] = 0.f;
    return;
  }
  const float* X = XC + (long)b*NN*FF;
  __shared__ float xs[8][FF];
  for (int e=t; e<8*FF; e+=256){
    int r=e>>7, k=e&127; int rr=r0+r;
    xs[r][k] = (rr<cnt) ? X[(long)rr*FF+k] : 0.f;
  }
  __syncthreads();
  float acc[8]={0.f,0.f,0.f,0.f,0.f,0.f,0.f,0.f};
  for (int k=0;k<FF;++k){
    float w = pW[k*2*FF + t];
    #pragma unroll
    for (int r=0;r<8;++r) acc[r]+=xs[r][k]*w;
  }
  float bb = pB[t];
  float kacc=0.f;
  #pragma unroll
  for (int r=0;r<8;++r){
    int rr=r0+r;
    if (rr>=cnt) continue;
    float v = acc[r]+bb;
    if (t<FF){ MEAN[(long)b*NN*FF + (long)rr*FF + t]=v; kacc += v*v; }
    else kacc += __expf(v)-v-1.f;
  }
  #pragma unroll
  for (int o=32;o;o>>=1) kacc += __shfl_down(kacc,o);
  __shared__ float rw[4];
  if ((t&63)==0) rw[t>>6]=kacc;
  __syncthreads();
  if (t==0) KPART[b*NPB + bx] = rw[0]+rw[1]+rw[2]+rw[3];
}

// ---- decoder partial reduction: sum_j w_j*h3_j over chunk ----
__global__ __launch_bounds__(128) void k_dec(const float* __restrict__ H3,
    const float* __restrict__ SJ3, const float* __restrict__ sN,
    const int* __restrict__ cntArr, float* __restrict__ DECP)
{
  int b=blockIdx.y, ch=blockIdx.x;
  int cnt=cntArr[b];
  int f=threadIdx.x;
  int r0=ch*96; int r1 = (r0+96 < cnt) ? r0+96 : cnt;
  float siN = sN[0];
  const float* H = H3 + (long)b*NN*FF;
  const float* SJ = SJ3 + (long)b*NN;
  float accV=0.f, accW=0.f;
  for (int r=r0;r<r1;++r){
    float sj=SJ[r]; float x=siN+sj;
    float e=(x>=0.f)? x : SLOPE*x;
    float w=__expf(e);
    accV += w*H[(long)r*FF+f];
    accW += w;
  }
  float* P = DECP + (long)(b*16+ch)*(FF+1);
  P[f]=accV;
  if (f==0) P[FF]=accW;
}

// ---- final: feats -> MLP head -> pred (fp32); kld reduced from partials ----
__global__ __launch_bounds__(128) void k_final(const float* __restrict__ DECP,
    const float* __restrict__ hN, const float* __restrict__ sN,
    const float* __restrict__ KPART, const int* __restrict__ cntArr,
    const float* __restrict__ W1, const float* __restrict__ b1,
    const float* __restrict__ W2, const float* __restrict__ b2,
    float* __restrict__ out)
{
  int f=threadIdx.x;
  __shared__ float feats[BB][FF];
  float siN=sN[0], sjN=sN[1];
  float xN=siN+sjN; float eN=(xN>=0.f)?xN:SLOPE*xN; float wN=__expf(eN);
  for (int b=0;b<BB;++b){
    float num=0.f, den=0.f;
    for (int c=0;c<16;++c){
      const float* P = DECP + (long)(b*16+c)*(FF+1);
      num += P[f]; den += P[FF];
    }
    num += wN*hN[f]; den += wN;
    float v=num/den;
    feats[b][f] = (v>0.f)? v : 0.f;
  }
  __syncthreads();
  __shared__ float rw[2];
  for (int b=0;b<BB;++b){
    float acc=0.f;
    for (int k=0;k<FF;++k) acc += feats[b][k]*W1[k*FF+f];
    acc += b1[f];
    acc = (acc>0.f)? acc : 0.f;
    float p = acc*W2[f];
    #pragma unroll
    for (int o=32;o;o>>=1) p += __shfl_down(p,o);
    if ((f&63)==0) rw[f>>6]=p;
    __syncthreads();
    if (f==0) out[b] = rw[0]+rw[1]+b2[0];
    __syncthreads();
  }
  float s=0.f;
  for (int b=0;b<BB;++b){
    float part=0.f;
    for (int c=f;c<NPB;c+=128) part += KPART[b*NPB + c];
    #pragma unroll
    for (int o=32;o;o>>=1) part += __shfl_down(part,o);
    if ((f&63)==0) rw[f>>6]=part;
    __syncthreads();
    float tot = rw[0]+rw[1];
    int c=cntArr[b]; float cf = (c>0)? (float)c : 1.f;
    s += 0.5f*tot/cf;
    __syncthreads();
  }
  if (f==0) out[16]=s;
}

extern "C" void kernel_launch(void* const* d_in, const int* in_sizes, int n_in,
                              void* d_out, int out_size, void* d_ws, size_t ws_size,
                              hipStream_t stream)
{
  const int*   data  = (const int*)d_in[0];
  const float* embed = (const float*)d_in[1];
  const float* encW  = (const float*)d_in[2];
  const float* encAs = (const float*)d_in[3];
  const float* encAd = (const float*)d_in[4];
  const float* pW    = (const float*)d_in[5];
  const float* pB    = (const float*)d_in[6];
  const float* decW  = (const float*)d_in[7];
  const float* decAs = (const float*)d_in[8];
  const float* decAd = (const float*)d_in[9];
  const float* oW1   = (const float*)d_in[10];
  const float* oB1   = (const float*)d_in[11];
  const float* oW2   = (const float*)d_in[12];
  const float* oB2   = (const float*)d_in[13];
  float* out = (float*)d_out;   // float32 output

  float* w = (float*)d_ws;
  long o = 0;
  float* H1   = w+o; o += (long)NN*FF;
  float* H2   = w+o; o += (long)BB*NN*FF;   // later reused as MEAN
  float* XC   = w+o; o += (long)BB*NN*FF;   // layer outputs; later reused as H3
  float* SI1  = w+o; o += NN;
  float* SJ1  = w+o; o += NN;
  float* SI2  = w+o; o += (long)BB*NN;
  float* SJ2  = w+o; o += (long)BB*NN;
  float* KPART= w+o; o += (long)BB*NPB;
  float* hN   = w+o; o += FF;
  float* sN   = w+o; o += 2;
  float* DECP = w+o; o += (long)BB*16*(FF+1);
  int* act = (int*)(w+o); o += (long)BB*NN;
  int* cnt = (int*)(w+o); o += BB;
  (void)in_sizes; (void)n_in; (void)out_size; (void)ws_size;

  k_compact<<<BB,256,0,stream>>>(data, act, cnt);
  k_hn<<<1,128,0,stream>>>(embed, decW, decAs, decAd, hN, sN);
  // encoder layer 1 (shared h/si/sj across samples)
  k_rowmm<<<dim3(NN/8,1),128,0,stream>>>(embed, 0L,
      encW, encAs, encAd, H1, SI1, SJ1, nullptr);
  k_agg_sep<<<BB,256,0,stream>>>(SJ1, SI1, act, H1, 0L, 0L, cnt, XC);
  // encoder layer 2 (per-sample, compacted)
  k_rowmm<<<dim3(NN/8,BB),128,0,stream>>>(XC, (long)NN*FF,
      encW + FF*FF, encAs + FF, encAd + FF, H2, SI2, SJ2, cnt);
  k_agg_sep<<<BB,256,0,stream>>>(SJ2, SI2, nullptr, H2, (long)NN*FF, (long)NN, cnt, XC);
  // param head + kld partials (XC -> MEAN into H2)
  k_par<<<dim3(NPB,BB),256,0,stream>>>(XC, pW, pB, H2 /*MEAN*/, KPART, cnt);
  // decoder projection + scores (MEAN=H2 -> H3=XC)
  k_rowmm<<<dim3(NN/8,BB),128,0,stream>>>(H2 /*MEAN*/, (long)NN*FF,
      decW, decAs, decAd, XC /*H3*/, SI2, SJ2, cnt);
  k_dec<<<dim3(16,BB),128,0,stream>>>(XC /*H3*/, SJ2, sN, cnt, DECP);
  k_final<<<1,128,0,stream>>>(DECP, hN, sN, KPART, cnt, oW1, oB1, oW2, oB2, out);
}

// Round 10
// 393.091 us; speedup vs baseline: 2.8834x; 2.8064x over previous
//
#include <hip/hip_runtime.h>

#define BB 16
#define NN 1536
#define FF 128
#define SLOPE 0.2f
#define NS 2048
#define CHS 128
#define NCH 12          // NN/CHS
#define TI 16
#define NPB (NN/8)      // 192 k_par blocks per sample

// ---- per-sample active-node compaction (ordered), cnt ----
__global__ __launch_bounds__(256) void k_compact(const int* __restrict__ data,
    int* __restrict__ act, int* __restrict__ cnt)
{
  int b = blockIdx.x, t = threadIdx.x;
  const int PER = NN/256;                 // 6
  int local[NN/256]; int nl = 0;
  int base = t*PER;
  #pragma unroll
  for (int u=0; u<PER; ++u){
    if (data[b*NN + base + u] != 0) local[nl++] = base+u;
  }
  __shared__ int s[256];
  s[t]=nl; __syncthreads();
  if (t==0){ int run=0; for (int i=0;i<256;i++){ int v=s[i]; s[i]=run; run+=v; } cnt[b]=run; }
  __syncthreads();
  int o = s[t];
  for (int u=0; u<nl; ++u) act[b*NN + o + u] = local[u];
}

// ---- h_N = embed[-1] @ dec_W, si_N, sj_N (sample-independent) ----
__global__ __launch_bounds__(128) void k_hn(const float* __restrict__ embed,
    const float* __restrict__ decW, const float* __restrict__ aS, const float* __restrict__ aD,
    float* __restrict__ hN, float* __restrict__ sN)
{
  int f = threadIdx.x;
  float acc = 0.f;
  for (int k=0;k<FF;++k) acc += embed[(long)NN*FF + k] * decW[k*FF + f];
  hN[f] = acc;
  float ps = acc * aS[f];
  float pd = acc * aD[f];
  #pragma unroll
  for (int o=32;o;o>>=1){ ps += __shfl_down(ps,o); pd += __shfl_down(pd,o); }
  __shared__ float rs[2][2];
  if ((f&63)==0){ rs[0][f>>6]=ps; rs[1][f>>6]=pd; }
  __syncthreads();
  if (f==0){ sN[0]=rs[0][0]+rs[0][1]; sN[1]=rs[1][0]+rs[1][1]; }
}

// ---- generic row-matmul: H = X @ W (F x F), SI = H@aSrc, SJ = H@aDst ----
__global__ __launch_bounds__(128) void k_rowmm(const float* __restrict__ Xv, long xStride,
    const float* __restrict__ W, const float* __restrict__ aS, const float* __restrict__ aD,
    float* __restrict__ Hb, float* __restrict__ SIb, float* __restrict__ SJb,
    const int* __restrict__ cntArr)
{
  int b = blockIdx.y;
  int cnt = cntArr ? cntArr[b] : NN;
  int r0 = blockIdx.x*8;
  if (r0 >= cnt) return;
  int f = threadIdx.x;
  float* H  = Hb  + (long)b*NN*FF;
  float* SI = SIb + (long)b*NN;
  float* SJ = SJb + (long)b*NN;
  __shared__ float xs[8][FF];
  #pragma unroll
  for (int r=0;r<8;++r){
    int rr=r0+r; float v=0.f;
    if (rr<cnt) v = Xv[(long)b*xStride + (long)rr*FF + f];
    xs[r][f]=v;
  }
  __syncthreads();
  float acc[8]={0.f,0.f,0.f,0.f,0.f,0.f,0.f,0.f};
  for (int k=0;k<FF;++k){
    float w = W[k*FF + f];
    #pragma unroll
    for (int r=0;r<8;++r) acc[r] += xs[r][k]*w;
  }
  float as = aS[f], ad = aD[f];
  __shared__ float red[2][8][2];
  #pragma unroll
  for (int r=0;r<8;++r){
    int rr=r0+r;
    if (rr<cnt) H[(long)rr*FF + f] = acc[r];
    float ps = acc[r]*as, pd = acc[r]*ad;
    #pragma unroll
    for (int o=32;o;o>>=1){ ps += __shfl_down(ps,o); pd += __shfl_down(pd,o); }
    if ((f&63)==0){ red[0][r][f>>6]=ps; red[1][r][f>>6]=pd; }
  }
  __syncthreads();
  if (f<8){
    int rr=r0+f;
    if (rr<cnt){ SI[rr]=red[0][f][0]+red[0][f][1]; SJ[rr]=red[1][f][0]+red[1][f][1]; }
  }
}

// ---- agg stage 1: sort (sj, Hrow) asc; inclusive scan of scalar weights ----
__global__ __launch_bounds__(1024) void k_sort(
    const float* __restrict__ SJb, long sStride, const int* __restrict__ actB,
    const int* __restrict__ cntArr,
    float* __restrict__ keyG, int* __restrict__ pjG,
    float* __restrict__ SBG, float* __restrict__ SDG)
{
  int b = blockIdx.x, t = threadIdx.x;
  int cnt = cntArr[b];
  const float* SJ = SJb + (long)b*sStride;
  const int* act = actB ? actB + b*NN : nullptr;
  __shared__ float key[NS]; __shared__ int pj[NS];
  __shared__ float sb[NS]; __shared__ float sd[NS];
  int NSort = 32; while (NSort < cnt) NSort <<= 1;    // <= 2048

  for (int e=t; e<NSort; e+=1024){
    if (e<cnt){ int io = act ? act[e] : e; key[e]=SJ[io]; pj[e]=io; }
    else { key[e]=__builtin_inff(); pj[e]=0; }
  }
  __syncthreads();
  for (int k=2; k<=NSort; k<<=1){
    for (int j=k>>1; j>0; j>>=1){
      for (int e=t; e<NSort; e+=1024){
        int l = e ^ j;
        if (l > e){
          bool asc = ((e & k) == 0);
          float a0=key[e], a1=key[l];
          if (asc ? (a0>a1) : (a0<a1)){
            key[e]=a1; key[l]=a0; int p=pj[e]; pj[e]=pj[l]; pj[l]=p;
          }
        }
      }
      __syncthreads();
    }
  }
  for (int e=t; e<NSort; e+=1024){
    if (e<cnt){ float kk=key[e]; sb[e]=__expf(kk); sd[e]=__expf(SLOPE*kk); }
    else { sb[e]=0.f; sd[e]=0.f; }
  }
  __syncthreads();
  // Hillis-Steele inclusive scan of sb, sd
  for (int off=1; off<NSort; off<<=1){
    float t0[2], t1[2]; int ne=0;
    for (int e=t; e<NSort; e+=1024){
      t0[ne] = (e>=off) ? sb[e-off] : 0.f;
      t1[ne] = (e>=off) ? sd[e-off] : 0.f;
      ne++;
    }
    __syncthreads();
    ne=0;
    for (int e=t; e<NSort; e+=1024){ sb[e]+=t0[ne]; sd[e]+=t1[ne]; ne++; }
    __syncthreads();
  }
  for (int e=t; e<cnt; e+=1024){
    keyG[(long)b*NN+e]=key[e]; pjG[(long)b*NN+e]=pj[e];
    SBG[(long)b*NN+e]=sb[e];   SDG[(long)b*NN+e]=sd[e];
  }
}

// ---- agg stage 2: within-chunk vector prefixes PP/PM over sorted j ----
__global__ __launch_bounds__(128) void k_chunk(
    const float* __restrict__ keyG, const int* __restrict__ pjG,
    const int* __restrict__ cntArr,
    const float* __restrict__ Hb, long hStride,
    float* __restrict__ PP, float* __restrict__ PM)
{
  int b = blockIdx.y, c = blockIdx.x, f = threadIdx.x;
  int cnt = cntArr[b];
  int k0 = c*CHS;
  if (k0 >= cnt) return;
  int k1 = k0+CHS; if (k1 > cnt) k1 = cnt;
  const float* H = Hb + (long)b*hStride;
  __shared__ int pjs[CHS]; __shared__ float wbs[CHS], wds[CHS];
  {
    int k = k0 + f;
    if (k < k1){
      float kk = keyG[(long)b*NN + k];
      pjs[f] = pjG[(long)b*NN + k];
      wbs[f] = __expf(kk);
      wds[f] = __expf(SLOPE*kk);
    }
  }
  __syncthreads();
  float accB=0.f, accD=0.f;
  for (int k=k0; k<k1; ++k){
    float hv = H[(long)pjs[k-k0]*FF + f];
    accB = fmaf(wbs[k-k0], hv, accB);
    accD = fmaf(wds[k-k0], hv, accD);
    PP[((long)b*NN + k)*FF + f] = accB;
    PM[((long)b*NN + k)*FF + f] = accD;
  }
}

// ---- agg stage 3: exclusive chunk offsets + grand totals ----
__global__ __launch_bounds__(128) void k_choff(
    const float* __restrict__ PP, const float* __restrict__ PM,
    const int* __restrict__ cntArr,
    float* __restrict__ GOB, float* __restrict__ GOD)
{
  int b = blockIdx.x, f = threadIdx.x;
  int cnt = cntArr[b];
  float rb=0.f, rd=0.f;
  for (int c=0; c<NCH; ++c){
    GOB[((long)b*(NCH+1)+c)*FF+f]=rb;
    GOD[((long)b*(NCH+1)+c)*FF+f]=rd;
    int k0=c*CHS;
    if (k0 < cnt){
      int kend = k0+CHS; if (kend > cnt) kend = cnt; kend -= 1;
      rb += PP[((long)b*NN+kend)*FF+f];
      rd += PM[((long)b*NN+kend)*FF+f];
    }
  }
  GOB[((long)b*(NCH+1)+NCH)*FF+f]=rb;   // grand total TB
  GOD[((long)b*(NCH+1)+NCH)*FF+f]=rd;
}

// ---- agg stage 4: per-row binary search + combine, elu, store ----
__global__ __launch_bounds__(128) void k_aggout(
    const float* __restrict__ keyG, const float* __restrict__ SBG, const float* __restrict__ SDG,
    const float* __restrict__ PP, const float* __restrict__ PM,
    const float* __restrict__ GOB, const float* __restrict__ GOD,
    const float* __restrict__ SIb, long sStride, const int* __restrict__ actB,
    const int* __restrict__ cntArr, float* __restrict__ XoB)
{
  int b = blockIdx.y;
  int cnt = cntArr[b];
  int r0 = blockIdx.x*TI;
  if (r0 >= cnt) return;
  int f = threadIdx.x;
  const float* SI = SIb + (long)b*sStride;
  const int* act = actB ? actB + b*NN : nullptr;
  const float* key = keyG + (long)b*NN;
  float* xo = XoB + (long)b*NN*FF;
  __shared__ int kk[TI]; __shared__ float sis[TI];
  if (f < TI){
    int r = r0 + f;
    float si=0.f; int k=0;
    if (r < cnt){
      int io = act ? act[r] : r;
      si = SI[io];
      float th = -si;
      int lo=0, hi=cnt;
      while (lo<hi){ int mid=(lo+hi)>>1; if (key[mid]<=th) lo=mid+1; else hi=mid; }
      k = lo;
    }
    kk[f]=k; sis[f]=si;
  }
  __syncthreads();
  float TB  = GOB[((long)b*(NCH+1)+NCH)*FF+f];
  float TBs = SBG[(long)b*NN + (cnt-1)];
  int rmax = cnt - r0; if (rmax > TI) rmax = TI;
  for (int r=0; r<rmax; ++r){
    int k = kk[r]; float si = sis[r];
    float PB=0.f, PD=0.f, SBv=0.f, SDv=0.f;
    if (k > 0){
      int c = (k-1)/CHS;
      PB = PP[((long)b*NN+(k-1))*FF+f] + GOB[((long)b*(NCH+1)+c)*FF+f];
      PD = PM[((long)b*NN+(k-1))*FF+f] + GOD[((long)b*(NCH+1)+c)*FF+f];
      SBv = SBG[(long)b*NN+(k-1)];
      SDv = SDG[(long)b*NN+(k-1)];
    }
    float ai=__expf(si), ci=__expf(SLOPE*si);
    float num = ai*(TB -PB ) + ci*PD;
    float den = ai*(TBs-SBv) + ci*SDv;
    float o2 = num/den;
    xo[(long)(r0+r)*FF + f] = (o2>0.f)? o2 : (__expf(o2)-1.f);
  }
}

// ---- par = x2 @ param_W + b; store mean; write per-block kld partial ----
__global__ __launch_bounds__(256) void k_par(const float* __restrict__ XC,
    const float* __restrict__ pW, const float* __restrict__ pB,
    float* __restrict__ MEAN, float* __restrict__ KPART, const int* __restrict__ cntArr)
{
  int b = blockIdx.y; int cnt = cntArr[b];
  int bx = blockIdx.x;
  int r0 = bx*8;
  int t = threadIdx.x;
  if (r0>=cnt){
    if (t==0) KPART[b*NPB + bx] = 0.f;
    return;
  }
  const float* X = XC + (long)b*NN*FF;
  __shared__ float xs[8][FF];
  for (int e=t; e<8*FF; e+=256){
    int r=e>>7, k=e&127; int rr=r0+r;
    xs[r][k] = (rr<cnt) ? X[(long)rr*FF+k] : 0.f;
  }
  __syncthreads();
  float acc[8]={0.f,0.f,0.f,0.f,0.f,0.f,0.f,0.f};
  for (int k=0;k<FF;++k){
    float w = pW[k*2*FF + t];
    #pragma unroll
    for (int r=0;r<8;++r) acc[r]+=xs[r][k]*w;
  }
  float bb = pB[t];
  float kacc=0.f;
  #pragma unroll
  for (int r=0;r<8;++r){
    int rr=r0+r;
    if (rr>=cnt) continue;
    float v = acc[r]+bb;
    if (t<FF){ MEAN[(long)b*NN*FF + (long)rr*FF + t]=v; kacc += v*v; }
    else kacc += __expf(v)-v-1.f;
  }
  #pragma unroll
  for (int o=32;o;o>>=1) kacc += __shfl_down(kacc,o);
  __shared__ float rw[4];
  if ((t&63)==0) rw[t>>6]=kacc;
  __syncthreads();
  if (t==0) KPART[b*NPB + bx] = rw[0]+rw[1]+rw[2]+rw[3];
}

// ---- decoder partial reduction: sum_j w_j*h3_j over chunk ----
__global__ __launch_bounds__(128) void k_dec(const float* __restrict__ H3,
    const float* __restrict__ SJ3, const float* __restrict__ sN,
    const int* __restrict__ cntArr, float* __restrict__ DECP)
{
  int b=blockIdx.y, ch=blockIdx.x;
  int cnt=cntArr[b];
  int f=threadIdx.x;
  int r0=ch*96; int r1 = (r0+96 < cnt) ? r0+96 : cnt;
  float siN = sN[0];
  const float* H = H3 + (long)b*NN*FF;
  const float* SJ = SJ3 + (long)b*NN;
  float accV=0.f, accW=0.f;
  for (int r=r0;r<r1;++r){
    float sj=SJ[r]; float x=siN+sj;
    float e=(x>=0.f)? x : SLOPE*x;
    float w=__expf(e);
    accV += w*H[(long)r*FF+f];
    accW += w;
  }
  float* P = DECP + (long)(b*16+ch)*(FF+1);
  P[f]=accV;
  if (f==0) P[FF]=accW;
}

// ---- final: feats -> MLP head -> pred (fp32); kld reduced from partials ----
__global__ __launch_bounds__(128) void k_final(const float* __restrict__ DECP,
    const float* __restrict__ hN, const float* __restrict__ sN,
    const float* __restrict__ KPART, const int* __restrict__ cntArr,
    const float* __restrict__ W1, const float* __restrict__ b1,
    const float* __restrict__ W2, const float* __restrict__ b2,
    float* __restrict__ out)
{
  int f=threadIdx.x;
  __shared__ float feats[BB][FF];
  float siN=sN[0], sjN=sN[1];
  float xN=siN+sjN; float eN=(xN>=0.f)?xN:SLOPE*xN; float wN=__expf(eN);
  for (int b=0;b<BB;++b){
    float num=0.f, den=0.f;
    for (int c=0;c<16;++c){
      const float* P = DECP + (long)(b*16+c)*(FF+1);
      num += P[f]; den += P[FF];
    }
    num += wN*hN[f]; den += wN;
    float v=num/den;
    feats[b][f] = (v>0.f)? v : 0.f;
  }
  __syncthreads();
  __shared__ float rw[2];
  for (int b=0;b<BB;++b){
    float acc=0.f;
    for (int k=0;k<FF;++k) acc += feats[b][k]*W1[k*FF+f];
    acc += b1[f];
    acc = (acc>0.f)? acc : 0.f;
    float p = acc*W2[f];
    #pragma unroll
    for (int o=32;o;o>>=1) p += __shfl_down(p,o);
    if ((f&63)==0) rw[f>>6]=p;
    __syncthreads();
    if (f==0) out[b] = rw[0]+rw[1]+b2[0];
    __syncthreads();
  }
  float s=0.f;
  for (int b=0;b<BB;++b){
    float part=0.f;
    for (int c=f;c<NPB;c+=128) part += KPART[b*NPB + c];
    #pragma unroll
    for (int o=32;o;o>>=1) part += __shfl_down(part,o);
    if ((f&63)==0) rw[f>>6]=part;
    __syncthreads();
    float tot = rw[0]+rw[1];
    int c=cntArr[b]; float cf = (c>0)? (float)c : 1.f;
    s += 0.5f*tot/cf;
    __syncthreads();
  }
  if (f==0) out[16]=s;
}

extern "C" void kernel_launch(void* const* d_in, const int* in_sizes, int n_in,
                              void* d_out, int out_size, void* d_ws, size_t ws_size,
                              hipStream_t stream)
{
  const int*   data  = (const int*)d_in[0];
  const float* embed = (const float*)d_in[1];
  const float* encW  = (const float*)d_in[2];
  const float* encAs = (const float*)d_in[3];
  const float* encAd = (const float*)d_in[4];
  const float* pW    = (const float*)d_in[5];
  const float* pB    = (const float*)d_in[6];
  const float* decW  = (const float*)d_in[7];
  const float* decAs = (const float*)d_in[8];
  const float* decAd = (const float*)d_in[9];
  const float* oW1   = (const float*)d_in[10];
  const float* oB1   = (const float*)d_in[11];
  const float* oW2   = (const float*)d_in[12];
  const float* oB2   = (const float*)d_in[13];
  float* out = (float*)d_out;

  float* w = (float*)d_ws;
  long o = 0;
  float* H1   = w+o; o += (long)NN*FF;
  float* H2   = w+o; o += (long)BB*NN*FF;   // later reused as MEAN
  float* XC   = w+o; o += (long)BB*NN*FF;   // layer outputs; later reused as H3
  float* PP   = w+o; o += (long)BB*NN*FF;
  float* PM   = w+o; o += (long)BB*NN*FF;
  float* SI1  = w+o; o += NN;
  float* SJ1  = w+o; o += NN;
  float* SI2  = w+o; o += (long)BB*NN;
  float* SJ2  = w+o; o += (long)BB*NN;
  float* KPART= w+o; o += (long)BB*NPB;
  float* hN   = w+o; o += FF;
  float* sN   = w+o; o += 2;
  float* DECP = w+o; o += (long)BB*16*(FF+1);
  float* keyG = w+o; o += (long)BB*NN;
  float* SBG  = w+o; o += (long)BB*NN;
  float* SDG  = w+o; o += (long)BB*NN;
  float* GOB  = w+o; o += (long)BB*(NCH+1)*FF;
  float* GOD  = w+o; o += (long)BB*(NCH+1)*FF;
  int* act = (int*)(w+o); o += (long)BB*NN;
  int* pjG = (int*)(w+o); o += (long)BB*NN;
  int* cnt = (int*)(w+o); o += BB;
  (void)in_sizes; (void)n_in; (void)out_size; (void)ws_size;

  k_compact<<<BB,256,0,stream>>>(data, act, cnt);
  k_hn<<<1,128,0,stream>>>(embed, decW, decAs, decAd, hN, sN);
  // encoder layer 1 (shared h/si/sj across samples)
  k_rowmm<<<dim3(NN/8,1),128,0,stream>>>(embed, 0L,
      encW, encAs, encAd, H1, SI1, SJ1, nullptr);
  k_sort  <<<BB,1024,0,stream>>>(SJ1, 0L, act, cnt, keyG, pjG, SBG, SDG);
  k_chunk <<<dim3(NCH,BB),128,0,stream>>>(keyG, pjG, cnt, H1, 0L, PP, PM);
  k_choff <<<BB,128,0,stream>>>(PP, PM, cnt, GOB, GOD);
  k_aggout<<<dim3(NN/TI,BB),128,0,stream>>>(keyG, SBG, SDG, PP, PM, GOB, GOD,
      SI1, 0L, act, cnt, XC);
  // encoder layer 2 (per-sample, compacted)
  k_rowmm<<<dim3(NN/8,BB),128,0,stream>>>(XC, (long)NN*FF,
      encW + FF*FF, encAs + FF, encAd + FF, H2, SI2, SJ2, cnt);
  k_sort  <<<BB,1024,0,stream>>>(SJ2, (long)NN, nullptr, cnt, keyG, pjG, SBG, SDG);
  k_chunk <<<dim3(NCH,BB),128,0,stream>>>(keyG, pjG, cnt, H2, (long)NN*FF, PP, PM);
  k_choff <<<BB,128,0,stream>>>(PP, PM, cnt, GOB, GOD);
  k_aggout<<<dim3(NN/TI,BB),128,0,stream>>>(keyG, SBG, SDG, PP, PM, GOB, GOD,
      SI2, (long)NN, nullptr, cnt, XC);
  // param head + kld partials (XC -> MEAN into H2)
  k_par<<<dim3(NPB,BB),256,0,stream>>>(XC, pW, pB, H2 /*MEAN*/, KPART, cnt);
  // decoder projection + scores (MEAN=H2 -> H3=XC)
  k_rowmm<<<dim3(NN/8,BB),128,0,stream>>>(H2 /*MEAN*/, (long)NN*FF,
      decW, decAs, decAd, XC /*H3*/, SI2, SJ2, cnt);
  k_dec<<<dim3(16,BB),128,0,stream>>>(XC /*H3*/, SJ2, sN, cnt, DECP);
  k_final<<<1,128,0,stream>>>(DECP, hN, sN, KPART, cnt, oW1, oB1, oW2, oB2, out);
}

// Round 11
// 350.183 us; speedup vs baseline: 3.2367x; 1.1225x over previous
//
#include <hip/hip_runtime.h>

#define BB 16
#define NN 1536
#define FF 128
#define SLOPE 0.2f
#define NS 2048
#define CHS 128
#define NCH 12          // NN/CHS
#define TI 16
#define NPB (NN/8)      // 192 k_par blocks per sample

// ---- fused: blocks 0..15 = per-sample compaction; block 16 = h_N/s_N ----
__global__ __launch_bounds__(256) void k_pre(const int* __restrict__ data,
    const float* __restrict__ embed, const float* __restrict__ decW,
    const float* __restrict__ aS, const float* __restrict__ aD,
    int* __restrict__ act, int* __restrict__ cnt,
    float* __restrict__ hN, float* __restrict__ sN)
{
  int b = blockIdx.x, t = threadIdx.x;
  if (b < BB){
    const int PER = NN/256;                 // 6
    int local[NN/256]; int nl = 0;
    int base = t*PER;
    #pragma unroll
    for (int u=0; u<PER; ++u){
      if (data[b*NN + base + u] != 0) local[nl++] = base+u;
    }
    __shared__ int s[256];
    s[t]=nl; __syncthreads();
    if (t==0){ int run=0; for (int i=0;i<256;i++){ int v=s[i]; s[i]=run; run+=v; } cnt[b]=run; }
    __syncthreads();
    int o = s[t];
    for (int u=0; u<nl; ++u) act[b*NN + o + u] = local[u];
  } else {
    __shared__ float rs[2][2];
    if (t < FF){
      float acc = 0.f;
      for (int k=0;k<FF;++k) acc += embed[(long)NN*FF + k] * decW[k*FF + t];
      hN[t] = acc;
      float ps = acc * aS[t];
      float pd = acc * aD[t];
      #pragma unroll
      for (int o=32;o;o>>=1){ ps += __shfl_down(ps,o); pd += __shfl_down(pd,o); }
      if ((t&63)==0){ rs[0][t>>6]=ps; rs[1][t>>6]=pd; }
    }
    __syncthreads();
    if (t==0){ sN[0]=rs[0][0]+rs[0][1]; sN[1]=rs[1][0]+rs[1][1]; }
  }
}

// ---- generic row-matmul: H = X @ W (F x F), SI = H@aSrc, SJ = H@aDst ----
__global__ __launch_bounds__(128) void k_rowmm(const float* __restrict__ Xv, long xStride,
    const float* __restrict__ W, const float* __restrict__ aS, const float* __restrict__ aD,
    float* __restrict__ Hb, float* __restrict__ SIb, float* __restrict__ SJb,
    const int* __restrict__ cntArr)
{
  int b = blockIdx.y;
  int cnt = cntArr ? cntArr[b] : NN;
  int r0 = blockIdx.x*8;
  if (r0 >= cnt) return;
  int f = threadIdx.x;
  float* H  = Hb  + (long)b*NN*FF;
  float* SI = SIb + (long)b*NN;
  float* SJ = SJb + (long)b*NN;
  __shared__ float xs[8][FF];
  #pragma unroll
  for (int r=0;r<8;++r){
    int rr=r0+r; float v=0.f;
    if (rr<cnt) v = Xv[(long)b*xStride + (long)rr*FF + f];
    xs[r][f]=v;
  }
  __syncthreads();
  float acc[8]={0.f,0.f,0.f,0.f,0.f,0.f,0.f,0.f};
  for (int k=0;k<FF;++k){
    float w = W[k*FF + f];
    #pragma unroll
    for (int r=0;r<8;++r) acc[r] += xs[r][k]*w;
  }
  float as = aS[f], ad = aD[f];
  __shared__ float red[2][8][2];
  #pragma unroll
  for (int r=0;r<8;++r){
    int rr=r0+r;
    if (rr<cnt) H[(long)rr*FF + f] = acc[r];
    float ps = acc[r]*as, pd = acc[r]*ad;
    #pragma unroll
    for (int o=32;o;o>>=1){ ps += __shfl_down(ps,o); pd += __shfl_down(pd,o); }
    if ((f&63)==0){ red[0][r][f>>6]=ps; red[1][r][f>>6]=pd; }
  }
  __syncthreads();
  if (f<8){
    int rr=r0+f;
    if (rr<cnt){ SI[rr]=red[0][f][0]+red[0][f][1]; SJ[rr]=red[1][f][0]+red[1][f][1]; }
  }
}

// ---- agg stage 1: sort (sj, Hrow) asc; inclusive scan of scalar weights ----
__global__ __launch_bounds__(1024) void k_sort(
    const float* __restrict__ SJb, long sStride, const int* __restrict__ actB,
    const int* __restrict__ cntArr,
    float* __restrict__ keyG, int* __restrict__ pjG,
    float* __restrict__ SBG, float* __restrict__ SDG)
{
  int b = blockIdx.x, t = threadIdx.x;
  int cnt = cntArr[b];
  const float* SJ = SJb + (long)b*sStride;
  const int* act = actB ? actB + b*NN : nullptr;
  __shared__ float key[NS]; __shared__ int pj[NS];
  __shared__ float sb[NS]; __shared__ float sd[NS];
  int NSort = 32; while (NSort < cnt) NSort <<= 1;    // <= 2048

  for (int e=t; e<NSort; e+=1024){
    if (e<cnt){ int io = act ? act[e] : e; key[e]=SJ[io]; pj[e]=io; }
    else { key[e]=__builtin_inff(); pj[e]=0; }
  }
  __syncthreads();
  for (int k=2; k<=NSort; k<<=1){
    for (int j=k>>1; j>0; j>>=1){
      for (int e=t; e<NSort; e+=1024){
        int l = e ^ j;
        if (l > e){
          bool asc = ((e & k) == 0);
          float a0=key[e], a1=key[l];
          if (asc ? (a0>a1) : (a0<a1)){
            key[e]=a1; key[l]=a0; int p=pj[e]; pj[e]=pj[l]; pj[l]=p;
          }
        }
      }
      __syncthreads();
    }
  }
  for (int e=t; e<NSort; e+=1024){
    if (e<cnt){ float kk=key[e]; sb[e]=__expf(kk); sd[e]=__expf(SLOPE*kk); }
    else { sb[e]=0.f; sd[e]=0.f; }
  }
  __syncthreads();
  // Hillis-Steele inclusive scan of sb, sd
  for (int off=1; off<NSort; off<<=1){
    float t0[2], t1[2]; int ne=0;
    for (int e=t; e<NSort; e+=1024){
      t0[ne] = (e>=off) ? sb[e-off] : 0.f;
      t1[ne] = (e>=off) ? sd[e-off] : 0.f;
      ne++;
    }
    __syncthreads();
    ne=0;
    for (int e=t; e<NSort; e+=1024){ sb[e]+=t0[ne]; sd[e]+=t1[ne]; ne++; }
    __syncthreads();
  }
  for (int e=t; e<cnt; e+=1024){
    keyG[(long)b*NN+e]=key[e]; pjG[(long)b*NN+e]=pj[e];
    SBG[(long)b*NN+e]=sb[e];   SDG[(long)b*NN+e]=sd[e];
  }
}

// ---- agg stage 2: within-chunk vector prefixes PP/PM over sorted j ----
__global__ __launch_bounds__(128) void k_chunk(
    const float* __restrict__ keyG, const int* __restrict__ pjG,
    const int* __restrict__ cntArr,
    const float* __restrict__ Hb, long hStride,
    float* __restrict__ PP, float* __restrict__ PM)
{
  int b = blockIdx.y, c = blockIdx.x, f = threadIdx.x;
  int cnt = cntArr[b];
  int k0 = c*CHS;
  if (k0 >= cnt) return;
  int k1 = k0+CHS; if (k1 > cnt) k1 = cnt;
  const float* H = Hb + (long)b*hStride;
  __shared__ int pjs[CHS]; __shared__ float wbs[CHS], wds[CHS];
  {
    int k = k0 + f;
    if (k < k1){
      float kk = keyG[(long)b*NN + k];
      pjs[f] = pjG[(long)b*NN + k];
      wbs[f] = __expf(kk);
      wds[f] = __expf(SLOPE*kk);
    }
  }
  __syncthreads();
  float accB=0.f, accD=0.f;
  for (int k=k0; k<k1; ++k){
    float hv = H[(long)pjs[k-k0]*FF + f];
    accB = fmaf(wbs[k-k0], hv, accB);
    accD = fmaf(wds[k-k0], hv, accD);
    PP[((long)b*NN + k)*FF + f] = accB;
    PM[((long)b*NN + k)*FF + f] = accD;
  }
}

// ---- agg stage 3: per-row binary search + combine (self-computed offsets) ----
__global__ __launch_bounds__(128) void k_aggout(
    const float* __restrict__ keyG, const float* __restrict__ SBG, const float* __restrict__ SDG,
    const float* __restrict__ PP, const float* __restrict__ PM,
    const float* __restrict__ SIb, long sStride, const int* __restrict__ actB,
    const int* __restrict__ cntArr, float* __restrict__ XoB)
{
  int b = blockIdx.y;
  int cnt = cntArr[b];
  int r0 = blockIdx.x*TI;
  if (r0 >= cnt) return;
  int f = threadIdx.x;
  const float* SI = SIb + (long)b*sStride;
  const int* act = actB ? actB + b*NN : nullptr;
  float* xo = XoB + (long)b*NN*FF;
  __shared__ float keys[NN];
  __shared__ float offB[NCH][FF], offD[NCH][FF];
  __shared__ int kk[TI]; __shared__ float sis[TI];

  for (int e=f; e<cnt; e+=128) keys[e] = keyG[(long)b*NN + e];
  // chunk-exclusive offsets from chunk-end prefix rows (per-thread column f)
  float rb=0.f, rd=0.f;
  int nch = (cnt + CHS - 1)/CHS;
  for (int c=0; c<nch; ++c){
    offB[c][f]=rb; offD[c][f]=rd;
    int kend = (c+1)*CHS; if (kend > cnt) kend = cnt; kend -= 1;
    rb += PP[((long)b*NN+kend)*FF+f];
    rd += PM[((long)b*NN+kend)*FF+f];
  }
  float TB = rb;                      // grand total over j of e^sj h_j[f]
  __syncthreads();
  if (f < TI){
    int r = r0 + f;
    float si=0.f; int k=0;
    if (r < cnt){
      int io = act ? act[r] : r;
      si = SI[io];
      float th = -si;
      int lo=0, hi=cnt;
      while (lo<hi){ int mid=(lo+hi)>>1; if (keys[mid]<=th) lo=mid+1; else hi=mid; }
      k = lo;
    }
    kk[f]=k; sis[f]=si;
  }
  __syncthreads();
  float TBs = SBG[(long)b*NN + (cnt-1)];
  int rmax = cnt - r0; if (rmax > TI) rmax = TI;
  for (int r=0; r<rmax; ++r){
    int k = kk[r]; float si = sis[r];
    float PB=0.f, PD=0.f, SBv=0.f, SDv=0.f;
    if (k > 0){
      int c = (k-1)/CHS;
      PB = PP[((long)b*NN+(k-1))*FF+f] + offB[c][f];
      PD = PM[((long)b*NN+(k-1))*FF+f] + offD[c][f];
      SBv = SBG[(long)b*NN+(k-1)];
      SDv = SDG[(long)b*NN+(k-1)];
    }
    float ai=__expf(si), ci=__expf(SLOPE*si);
    float num = ai*(TB -PB ) + ci*PD;
    float den = ai*(TBs-SBv) + ci*SDv;
    float o2 = num/den;
    xo[(long)(r0+r)*FF + f] = (o2>0.f)? o2 : (__expf(o2)-1.f);
  }
}

// ---- par = x2 @ param_W + b; store mean; write per-block kld partial ----
__global__ __launch_bounds__(256) void k_par(const float* __restrict__ XC,
    const float* __restrict__ pW, const float* __restrict__ pB,
    float* __restrict__ MEAN, float* __restrict__ KPART, const int* __restrict__ cntArr)
{
  int b = blockIdx.y; int cnt = cntArr[b];
  int bx = blockIdx.x;
  int r0 = bx*8;
  int t = threadIdx.x;
  if (r0>=cnt){
    if (t==0) KPART[b*NPB + bx] = 0.f;
    return;
  }
  const float* X = XC + (long)b*NN*FF;
  __shared__ float xs[8][FF];
  for (int e=t; e<8*FF; e+=256){
    int r=e>>7, k=e&127; int rr=r0+r;
    xs[r][k] = (rr<cnt) ? X[(long)rr*FF+k] : 0.f;
  }
  __syncthreads();
  float acc[8]={0.f,0.f,0.f,0.f,0.f,0.f,0.f,0.f};
  for (int k=0;k<FF;++k){
    float w = pW[k*2*FF + t];
    #pragma unroll
    for (int r=0;r<8;++r) acc[r]+=xs[r][k]*w;
  }
  float bb = pB[t];
  float kacc=0.f;
  #pragma unroll
  for (int r=0;r<8;++r){
    int rr=r0+r;
    if (rr>=cnt) continue;
    float v = acc[r]+bb;
    if (t<FF){ MEAN[(long)b*NN*FF + (long)rr*FF + t]=v; kacc += v*v; }
    else kacc += __expf(v)-v-1.f;
  }
  #pragma unroll
  for (int o=32;o;o>>=1) kacc += __shfl_down(kacc,o);
  __shared__ float rw[4];
  if ((t&63)==0) rw[t>>6]=kacc;
  __syncthreads();
  if (t==0) KPART[b*NPB + bx] = rw[0]+rw[1]+rw[2]+rw[3];
}

// ---- decoder partial reduction: sum_j w_j*h3_j over chunk ----
__global__ __launch_bounds__(128) void k_dec(const float* __restrict__ H3,
    const float* __restrict__ SJ3, const float* __restrict__ sN,
    const int* __restrict__ cntArr, float* __restrict__ DECP)
{
  int b=blockIdx.y, ch=blockIdx.x;
  int cnt=cntArr[b];
  int f=threadIdx.x;
  int r0=ch*96; int r1 = (r0+96 < cnt) ? r0+96 : cnt;
  float siN = sN[0];
  const float* H = H3 + (long)b*NN*FF;
  const float* SJ = SJ3 + (long)b*NN;
  float accV=0.f, accW=0.f;
  for (int r=r0;r<r1;++r){
    float sj=SJ[r]; float x=siN+sj;
    float e=(x>=0.f)? x : SLOPE*x;
    float w=__expf(e);
    accV += w*H[(long)r*FF+f];
    accW += w;
  }
  float* P = DECP + (long)(b*16+ch)*(FF+1);
  P[f]=accV;
  if (f==0) P[FF]=accW;
}

// ---- head: blocks 0..15 = per-sample decoder-combine + MLP; block 16 = kld ----
__global__ __launch_bounds__(128) void k_head(const float* __restrict__ DECP,
    const float* __restrict__ hN, const float* __restrict__ sN,
    const float* __restrict__ KPART, const int* __restrict__ cntArr,
    const float* __restrict__ W1, const float* __restrict__ b1,
    const float* __restrict__ W2, const float* __restrict__ b2,
    float* __restrict__ out)
{
  int b = blockIdx.x;
  int f = threadIdx.x;
  __shared__ float rw[2];
  if (b < BB){
    float siN=sN[0], sjN=sN[1];
    float xN=siN+sjN; float eN=(xN>=0.f)?xN:SLOPE*xN; float wN=__expf(eN);
    float num=0.f, den=0.f;
    for (int c=0;c<16;++c){
      const float* P = DECP + (long)(b*16+c)*(FF+1);
      num += P[f]; den += P[FF];
    }
    num += wN*hN[f]; den += wN;
    float v = num/den;
    __shared__ float feats[FF];
    feats[f] = (v>0.f)? v : 0.f;
    __syncthreads();
    float acc=0.f;
    for (int k=0;k<FF;++k) acc += feats[k]*W1[k*FF+f];
    acc += b1[f];
    acc = (acc>0.f)? acc : 0.f;
    float p = acc*W2[f];
    #pragma unroll
    for (int o=32;o;o>>=1) p += __shfl_down(p,o);
    if ((f&63)==0) rw[f>>6]=p;
    __syncthreads();
    if (f==0) out[b] = rw[0]+rw[1]+b2[0];
  } else {
    float s=0.f;
    for (int bb=0;bb<BB;++bb){
      float part=0.f;
      for (int c=f;c<NPB;c+=128) part += KPART[bb*NPB + c];
      #pragma unroll
      for (int o=32;o;o>>=1) part += __shfl_down(part,o);
      if ((f&63)==0) rw[f>>6]=part;
      __syncthreads();
      float tot = rw[0]+rw[1];
      int c=cntArr[bb]; float cf = (c>0)? (float)c : 1.f;
      s += 0.5f*tot/cf;
      __syncthreads();
    }
    if (f==0) out[16]=s;
  }
}

extern "C" void kernel_launch(void* const* d_in, const int* in_sizes, int n_in,
                              void* d_out, int out_size, void* d_ws, size_t ws_size,
                              hipStream_t stream)
{
  const int*   data  = (const int*)d_in[0];
  const float* embed = (const float*)d_in[1];
  const float* encW  = (const float*)d_in[2];
  const float* encAs = (const float*)d_in[3];
  const float* encAd = (const float*)d_in[4];
  const float* pW    = (const float*)d_in[5];
  const float* pB    = (const float*)d_in[6];
  const float* decW  = (const float*)d_in[7];
  const float* decAs = (const float*)d_in[8];
  const float* decAd = (const float*)d_in[9];
  const float* oW1   = (const float*)d_in[10];
  const float* oB1   = (const float*)d_in[11];
  const float* oW2   = (const float*)d_in[12];
  const float* oB2   = (const float*)d_in[13];
  float* out = (float*)d_out;

  float* w = (float*)d_ws;
  long o = 0;
  float* H1   = w+o; o += (long)NN*FF;
  float* H2   = w+o; o += (long)BB*NN*FF;   // later reused as MEAN
  float* XC   = w+o; o += (long)BB*NN*FF;   // layer outputs; later reused as H3
  float* PP   = w+o; o += (long)BB*NN*FF;
  float* PM   = w+o; o += (long)BB*NN*FF;
  float* SI1  = w+o; o += NN;
  float* SJ1  = w+o; o += NN;
  float* SI2  = w+o; o += (long)BB*NN;
  float* SJ2  = w+o; o += (long)BB*NN;
  float* KPART= w+o; o += (long)BB*NPB;
  float* hN   = w+o; o += FF;
  float* sN   = w+o; o += 2;
  float* DECP = w+o; o += (long)BB*16*(FF+1);
  float* keyG = w+o; o += (long)BB*NN;
  float* SBG  = w+o; o += (long)BB*NN;
  float* SDG  = w+o; o += (long)BB*NN;
  int* act = (int*)(w+o); o += (long)BB*NN;
  int* pjG = (int*)(w+o); o += (long)BB*NN;
  int* cnt = (int*)(w+o); o += BB;
  (void)in_sizes; (void)n_in; (void)out_size; (void)ws_size;

  k_pre<<<BB+1,256,0,stream>>>(data, embed, decW, decAs, decAd, act, cnt, hN, sN);
  // encoder layer 1 (shared h/si/sj across samples)
  k_rowmm<<<dim3(NN/8,1),128,0,stream>>>(embed, 0L,
      encW, encAs, encAd, H1, SI1, SJ1, nullptr);
  k_sort  <<<BB,1024,0,stream>>>(SJ1, 0L, act, cnt, keyG, pjG, SBG, SDG);
  k_chunk <<<dim3(NCH,BB),128,0,stream>>>(keyG, pjG, cnt, H1, 0L, PP, PM);
  k_aggout<<<dim3(NN/TI,BB),128,0,stream>>>(keyG, SBG, SDG, PP, PM,
      SI1, 0L, act, cnt, XC);
  // encoder layer 2 (per-sample, compacted)
  k_rowmm<<<dim3(NN/8,BB),128,0,stream>>>(XC, (long)NN*FF,
      encW + FF*FF, encAs + FF, encAd + FF, H2, SI2, SJ2, cnt);
  k_sort  <<<BB,1024,0,stream>>>(SJ2, (long)NN, nullptr, cnt, keyG, pjG, SBG, SDG);
  k_chunk <<<dim3(NCH,BB),128,0,stream>>>(keyG, pjG, cnt, H2, (long)NN*FF, PP, PM);
  k_aggout<<<dim3(NN/TI,BB),128,0,stream>>>(keyG, SBG, SDG, PP, PM,
      SI2, (long)NN, nullptr, cnt, XC);
  // param head + kld partials (XC -> MEAN into H2)
  k_par<<<dim3(NPB,BB),256,0,stream>>>(XC, pW, pB, H2 /*MEAN*/, KPART, cnt);
  // decoder projection + scores (MEAN=H2 -> H3=XC)
  k_rowmm<<<dim3(NN/8,BB),128,0,stream>>>(H2 /*MEAN*/, (long)NN*FF,
      decW, decAs, decAd, XC /*H3*/, SI2, SJ2, cnt);
  k_dec<<<dim3(16,BB),128,0,stream>>>(XC /*H3*/, SJ2, sN, cnt, DECP);
  k_head<<<BB+1,128,0,stream>>>(DECP, hN, sN, KPART, cnt, oW1, oB1, oW2, oB2, out);
}

// Round 12
// 300.052 us; speedup vs baseline: 3.7775x; 1.1671x over previous
//
#include <hip/hip_runtime.h>

#define BB 16
#define NN 1536
#define FF 128
#define SLOPE 0.2f
#define NS 2048
#define CHS 64
#define NCH 24          // NN/CHS
#define TI 16
#define NPB (NN/8)      // 192 k_par blocks per sample

// ---- fused: compaction (layer1 only) + bitonic sort of sj + scalar scans ----
// grid BB+1 for layer 1 (block BB computes h_N/s_N); grid BB for layer 2.
__global__ __launch_bounds__(1024) void k_sortpre(
    const int* __restrict__ data,            // non-null => layer 1 (compact + gather via act)
    const float* __restrict__ embed, const float* __restrict__ decW,
    const float* __restrict__ aS, const float* __restrict__ aD,
    const float* __restrict__ SJb, long sStride,
    int* __restrict__ actG, int* __restrict__ cntG,
    float* __restrict__ hN, float* __restrict__ sN,
    float* __restrict__ keyG, int* __restrict__ pjG,
    float* __restrict__ SBG, float* __restrict__ SDG)
{
  int b = blockIdx.x, t = threadIdx.x;
  if (b == BB){
    __shared__ float rs[2][2];
    if (t < FF){
      float acc = 0.f;
      for (int k=0;k<FF;++k) acc += embed[(long)NN*FF + k] * decW[k*FF + t];
      hN[t] = acc;
      float ps = acc * aS[t];
      float pd = acc * aD[t];
      #pragma unroll
      for (int o=32;o;o>>=1){ ps += __shfl_down(ps,o); pd += __shfl_down(pd,o); }
      if ((t&63)==0){ rs[0][t>>6]=ps; rs[1][t>>6]=pd; }
    }
    __syncthreads();
    if (t==0){ sN[0]=rs[0][0]+rs[0][1]; sN[1]=rs[1][0]+rs[1][1]; }
    return;
  }

  __shared__ float key[NS]; __shared__ int pj[NS];
  __shared__ float sb[NS]; __shared__ float sd[NS];
  __shared__ int cntS;
  int cnt;
  if (data != nullptr){
    // compaction with first 256 threads (barriers unconditional)
    __shared__ int s[256];
    const int PER = NN/256;                  // 6
    int local[NN/256]; int nl = 0;
    if (t < 256){
      int base = t*PER;
      #pragma unroll
      for (int u=0; u<PER; ++u){
        if (data[b*NN + base + u] != 0) local[nl++] = base+u;
      }
      s[t]=nl;
    }
    __syncthreads();
    if (t==0){ int run=0; for (int i=0;i<256;i++){ int v=s[i]; s[i]=run; run+=v; }
               cntG[b]=run; cntS=run; }
    __syncthreads();
    if (t < 256){
      int o = s[t];
      for (int u=0; u<nl; ++u) actG[b*NN + o + u] = local[u];
    }
    __syncthreads();
    cnt = cntS;
  } else {
    cnt = cntG[b];
  }

  const float* SJ = SJb + (long)b*sStride;
  const int* act = (data != nullptr) ? actG + b*NN : nullptr;
  int NSort = 32; while (NSort < cnt) NSort <<= 1;    // <= 2048

  for (int e=t; e<NSort; e+=1024){
    if (e<cnt){ int io = act ? act[e] : e; key[e]=SJ[io]; pj[e]=io; }
    else { key[e]=__builtin_inff(); pj[e]=0; }
  }
  __syncthreads();
  for (int k=2; k<=NSort; k<<=1){
    for (int j=k>>1; j>0; j>>=1){
      for (int e=t; e<NSort; e+=1024){
        int l = e ^ j;
        if (l > e){
          bool asc = ((e & k) == 0);
          float a0=key[e], a1=key[l];
          if (asc ? (a0>a1) : (a0<a1)){
            key[e]=a1; key[l]=a0; int p=pj[e]; pj[e]=pj[l]; pj[l]=p;
          }
        }
      }
      __syncthreads();
    }
  }
  for (int e=t; e<NSort; e+=1024){
    if (e<cnt){ float kk=key[e]; sb[e]=__expf(kk); sd[e]=__expf(SLOPE*kk); }
    else { sb[e]=0.f; sd[e]=0.f; }
  }
  __syncthreads();
  // Hillis-Steele inclusive scan of sb, sd
  for (int off=1; off<NSort; off<<=1){
    float t0[2], t1[2]; int ne=0;
    for (int e=t; e<NSort; e+=1024){
      t0[ne] = (e>=off) ? sb[e-off] : 0.f;
      t1[ne] = (e>=off) ? sd[e-off] : 0.f;
      ne++;
    }
    __syncthreads();
    ne=0;
    for (int e=t; e<NSort; e+=1024){ sb[e]+=t0[ne]; sd[e]+=t1[ne]; ne++; }
    __syncthreads();
  }
  for (int e=t; e<cnt; e+=1024){
    keyG[(long)b*NN+e]=key[e]; pjG[(long)b*NN+e]=pj[e];
    SBG[(long)b*NN+e]=sb[e];   SDG[(long)b*NN+e]=sd[e];
  }
}

// ---- generic row-matmul: H = X @ W (F x F), SI = H@aSrc, SJ = H@aDst ----
__global__ __launch_bounds__(128) void k_rowmm(const float* __restrict__ Xv, long xStride,
    const float* __restrict__ W, const float* __restrict__ aS, const float* __restrict__ aD,
    float* __restrict__ Hb, float* __restrict__ SIb, float* __restrict__ SJb,
    const int* __restrict__ cntArr)
{
  int b = blockIdx.y;
  int cnt = cntArr ? cntArr[b] : NN;
  int r0 = blockIdx.x*8;
  if (r0 >= cnt) return;
  int f = threadIdx.x;
  float* H  = Hb  + (long)b*NN*FF;
  float* SI = SIb + (long)b*NN;
  float* SJ = SJb + (long)b*NN;
  __shared__ float xs[8][FF];
  #pragma unroll
  for (int r=0;r<8;++r){
    int rr=r0+r; float v=0.f;
    if (rr<cnt) v = Xv[(long)b*xStride + (long)rr*FF + f];
    xs[r][f]=v;
  }
  __syncthreads();
  float acc[8]={0.f,0.f,0.f,0.f,0.f,0.f,0.f,0.f};
  for (int k=0;k<FF;++k){
    float w = W[k*FF + f];
    #pragma unroll
    for (int r=0;r<8;++r) acc[r] += xs[r][k]*w;
  }
  float as = aS[f], ad = aD[f];
  __shared__ float red[2][8][2];
  #pragma unroll
  for (int r=0;r<8;++r){
    int rr=r0+r;
    if (rr<cnt) H[(long)rr*FF + f] = acc[r];
    float ps = acc[r]*as, pd = acc[r]*ad;
    #pragma unroll
    for (int o=32;o;o>>=1){ ps += __shfl_down(ps,o); pd += __shfl_down(pd,o); }
    if ((f&63)==0){ red[0][r][f>>6]=ps; red[1][r][f>>6]=pd; }
  }
  __syncthreads();
  if (f<8){
    int rr=r0+f;
    if (rr<cnt){ SI[rr]=red[0][f][0]+red[0][f][1]; SJ[rr]=red[1][f][0]+red[1][f][1]; }
  }
}

// ---- agg stage 2: within-chunk vector prefixes, 8-deep prefetch pipeline ----
__global__ __launch_bounds__(128) void k_chunk(
    const float* __restrict__ keyG, const int* __restrict__ pjG,
    const int* __restrict__ cntArr,
    const float* __restrict__ Hb, long hStride,
    float* __restrict__ PP, float* __restrict__ PM)
{
  int b = blockIdx.y, c = blockIdx.x, f = threadIdx.x;
  int cnt = cntArr[b];
  int k0 = c*CHS;
  if (k0 >= cnt) return;
  int k1 = k0+CHS; if (k1 > cnt) k1 = cnt;
  int kn = k1-k0;
  const float* H = Hb + (long)b*hStride + f;
  __shared__ int pjs[CHS]; __shared__ float wbs[CHS], wds[CHS];
  if (f < CHS && f < kn){
    float kk = keyG[(long)b*NN + k0 + f];
    pjs[f] = pjG[(long)b*NN + k0 + f];
    wbs[f] = __expf(kk);
    wds[f] = __expf(SLOPE*kk);
  }
  __syncthreads();
  float accB=0.f, accD=0.f;
  float hbuf[8];
  #pragma unroll
  for (int i=0;i<8;i++) hbuf[i] = (i<kn) ? H[(long)pjs[i]*FF] : 0.f;
  long obase = ((long)b*NN + k0)*FF + f;
  int k=0;
  for (; k+8<=kn; k+=8){
    #pragma unroll
    for (int u=0;u<8;u++){
      float hv = hbuf[u];
      int kp = k+u+8;
      hbuf[u] = (kp<kn) ? H[(long)pjs[kp]*FF] : 0.f;
      accB = fmaf(wbs[k+u], hv, accB);
      accD = fmaf(wds[k+u], hv, accD);
      PP[obase + (long)(k+u)*FF] = accB;
      PM[obase + (long)(k+u)*FF] = accD;
    }
  }
  for (; k<kn; ++k){
    float hv = H[(long)pjs[k]*FF];
    accB = fmaf(wbs[k], hv, accB);
    accD = fmaf(wds[k], hv, accD);
    PP[obase + (long)k*FF] = accB;
    PM[obase + (long)k*FF] = accD;
  }
}

// ---- agg stage 3: per-row binary search + combine (LDS-batched offsets) ----
__global__ __launch_bounds__(128) void k_aggout(
    const float* __restrict__ keyG, const float* __restrict__ SBG, const float* __restrict__ SDG,
    const float* __restrict__ PP, const float* __restrict__ PM,
    const float* __restrict__ SIb, long sStride, const int* __restrict__ actB,
    const int* __restrict__ cntArr, float* __restrict__ XoB)
{
  int b = blockIdx.y;
  int cnt = cntArr[b];
  int r0 = blockIdx.x*TI;
  if (r0 >= cnt) return;
  int f = threadIdx.x;
  const float* SI = SIb + (long)b*sStride;
  const int* act = actB ? actB + b*NN : nullptr;
  float* xo = XoB + (long)b*NN*FF;
  __shared__ float keys[NN];
  __shared__ float offB[NCH][FF], offD[NCH][FF];
  __shared__ int kk[TI]; __shared__ float sis[TI];

  for (int e=f; e<cnt; e+=128) keys[e] = keyG[(long)b*NN + e];
  // batch-load chunk-end prefix rows (independent loads, column f per thread)
  int nch = (cnt + CHS - 1)/CHS;
  for (int c=0; c<nch; ++c){
    int kend = (c+1)*CHS; if (kend > cnt) kend = cnt; kend -= 1;
    offB[c][f] = PP[((long)b*NN+kend)*FF+f];
    offD[c][f] = PM[((long)b*NN+kend)*FF+f];
  }
  // in-place exclusive scan (column f owned by this thread; no sync needed)
  float rb=0.f, rd=0.f;
  for (int c=0; c<nch; ++c){
    float tb=offB[c][f], td=offD[c][f];
    offB[c][f]=rb; offD[c][f]=rd;
    rb+=tb; rd+=td;
  }
  float TB = rb;                      // grand total over j of e^sj h_j[f]
  __syncthreads();
  if (f < TI){
    int r = r0 + f;
    float si=0.f; int k=0;
    if (r < cnt){
      int io = act ? act[r] : r;
      si = SI[io];
      float th = -si;
      int lo=0, hi=cnt;
      while (lo<hi){ int mid=(lo+hi)>>1; if (keys[mid]<=th) lo=mid+1; else hi=mid; }
      k = lo;
    }
    kk[f]=k; sis[f]=si;
  }
  __syncthreads();
  float TBs = SBG[(long)b*NN + (cnt-1)];
  int rmax = cnt - r0; if (rmax > TI) rmax = TI;
  for (int r=0; r<rmax; ++r){
    int k = kk[r]; float si = sis[r];
    float PB=0.f, PD=0.f, SBv=0.f, SDv=0.f;
    if (k > 0){
      int c = (k-1)/CHS;
      PB = PP[((long)b*NN+(k-1))*FF+f] + offB[c][f];
      PD = PM[((long)b*NN+(k-1))*FF+f] + offD[c][f];
      SBv = SBG[(long)b*NN+(k-1)];
      SDv = SDG[(long)b*NN+(k-1)];
    }
    float ai=__expf(si), ci=__expf(SLOPE*si);
    float num = ai*(TB -PB ) + ci*PD;
    float den = ai*(TBs-SBv) + ci*SDv;
    float o2 = num/den;
    xo[(long)(r0+r)*FF + f] = (o2>0.f)? o2 : (__expf(o2)-1.f);
  }
}

// ---- par = x2 @ param_W + b; store mean; write per-block kld partial ----
__global__ __launch_bounds__(256) void k_par(const float* __restrict__ XC,
    const float* __restrict__ pW, const float* __restrict__ pB,
    float* __restrict__ MEAN, float* __restrict__ KPART, const int* __restrict__ cntArr)
{
  int b = blockIdx.y; int cnt = cntArr[b];
  int bx = blockIdx.x;
  int r0 = bx*8;
  int t = threadIdx.x;
  if (r0>=cnt){
    if (t==0) KPART[b*NPB + bx] = 0.f;
    return;
  }
  const float* X = XC + (long)b*NN*FF;
  __shared__ float xs[8][FF];
  for (int e=t; e<8*FF; e+=256){
    int r=e>>7, k=e&127; int rr=r0+r;
    xs[r][k] = (rr<cnt) ? X[(long)rr*FF+k] : 0.f;
  }
  __syncthreads();
  float acc[8]={0.f,0.f,0.f,0.f,0.f,0.f,0.f,0.f};
  for (int k=0;k<FF;++k){
    float w = pW[k*2*FF + t];
    #pragma unroll
    for (int r=0;r<8;++r) acc[r]+=xs[r][k]*w;
  }
  float bb = pB[t];
  float kacc=0.f;
  #pragma unroll
  for (int r=0;r<8;++r){
    int rr=r0+r;
    if (rr>=cnt) continue;
    float v = acc[r]+bb;
    if (t<FF){ MEAN[(long)b*NN*FF + (long)rr*FF + t]=v; kacc += v*v; }
    else kacc += __expf(v)-v-1.f;
  }
  #pragma unroll
  for (int o=32;o;o>>=1) kacc += __shfl_down(kacc,o);
  __shared__ float rw[4];
  if ((t&63)==0) rw[t>>6]=kacc;
  __syncthreads();
  if (t==0) KPART[b*NPB + bx] = rw[0]+rw[1]+rw[2]+rw[3];
}

// ---- decoder partial reduction: sum_j w_j*h3_j over chunk ----
__global__ __launch_bounds__(128) void k_dec(const float* __restrict__ H3,
    const float* __restrict__ SJ3, const float* __restrict__ sN,
    const int* __restrict__ cntArr, float* __restrict__ DECP)
{
  int b=blockIdx.y, ch=blockIdx.x;
  int cnt=cntArr[b];
  int f=threadIdx.x;
  int r0=ch*96; int r1 = (r0+96 < cnt) ? r0+96 : cnt;
  float siN = sN[0];
  const float* H = H3 + (long)b*NN*FF;
  const float* SJ = SJ3 + (long)b*NN;
  float accV=0.f, accW=0.f;
  for (int r=r0;r<r1;++r){
    float sj=SJ[r]; float x=siN+sj;
    float e=(x>=0.f)? x : SLOPE*x;
    float w=__expf(e);
    accV += w*H[(long)r*FF+f];
    accW += w;
  }
  float* P = DECP + (long)(b*16+ch)*(FF+1);
  P[f]=accV;
  if (f==0) P[FF]=accW;
}

// ---- head: blocks 0..15 = per-sample decoder-combine + MLP; block 16 = kld ----
__global__ __launch_bounds__(128) void k_head(const float* __restrict__ DECP,
    const float* __restrict__ hN, const float* __restrict__ sN,
    const float* __restrict__ KPART, const int* __restrict__ cntArr,
    const float* __restrict__ W1, const float* __restrict__ b1,
    const float* __restrict__ W2, const float* __restrict__ b2,
    float* __restrict__ out)
{
  int b = blockIdx.x;
  int f = threadIdx.x;
  __shared__ float rw[2];
  if (b < BB){
    float siN=sN[0], sjN=sN[1];
    float xN=siN+sjN; float eN=(xN>=0.f)?xN:SLOPE*xN; float wN=__expf(eN);
    float num=0.f, den=0.f;
    for (int c=0;c<16;++c){
      const float* P = DECP + (long)(b*16+c)*(FF+1);
      num += P[f]; den += P[FF];
    }
    num += wN*hN[f]; den += wN;
    float v = num/den;
    __shared__ float feats[FF];
    feats[f] = (v>0.f)? v : 0.f;
    __syncthreads();
    float acc=0.f;
    for (int k=0;k<FF;++k) acc += feats[k]*W1[k*FF+f];
    acc += b1[f];
    acc = (acc>0.f)? acc : 0.f;
    float p = acc*W2[f];
    #pragma unroll
    for (int o=32;o;o>>=1) p += __shfl_down(p,o);
    if ((f&63)==0) rw[f>>6]=p;
    __syncthreads();
    if (f==0) out[b] = rw[0]+rw[1]+b2[0];
  } else {
    float s=0.f;
    for (int bb=0;bb<BB;++bb){
      float part=0.f;
      for (int c=f;c<NPB;c+=128) part += KPART[bb*NPB + c];
      #pragma unroll
      for (int o=32;o;o>>=1) part += __shfl_down(part,o);
      if ((f&63)==0) rw[f>>6]=part;
      __syncthreads();
      float tot = rw[0]+rw[1];
      int c=cntArr[bb]; float cf = (c>0)? (float)c : 1.f;
      s += 0.5f*tot/cf;
      __syncthreads();
    }
    if (f==0) out[16]=s;
  }
}

extern "C" void kernel_launch(void* const* d_in, const int* in_sizes, int n_in,
                              void* d_out, int out_size, void* d_ws, size_t ws_size,
                              hipStream_t stream)
{
  const int*   data  = (const int*)d_in[0];
  const float* embed = (const float*)d_in[1];
  const float* encW  = (const float*)d_in[2];
  const float* encAs = (const float*)d_in[3];
  const float* encAd = (const float*)d_in[4];
  const float* pW    = (const float*)d_in[5];
  const float* pB    = (const float*)d_in[6];
  const float* decW  = (const float*)d_in[7];
  const float* decAs = (const float*)d_in[8];
  const float* decAd = (const float*)d_in[9];
  const float* oW1   = (const float*)d_in[10];
  const float* oB1   = (const float*)d_in[11];
  const float* oW2   = (const float*)d_in[12];
  const float* oB2   = (const float*)d_in[13];
  float* out = (float*)d_out;

  float* w = (float*)d_ws;
  long o = 0;
  float* H1   = w+o; o += (long)NN*FF;
  float* H2   = w+o; o += (long)BB*NN*FF;   // later reused as MEAN
  float* XC   = w+o; o += (long)BB*NN*FF;   // layer outputs; later reused as H3
  float* PP   = w+o; o += (long)BB*NN*FF;
  float* PM   = w+o; o += (long)BB*NN*FF;
  float* SI1  = w+o; o += NN;
  float* SJ1  = w+o; o += NN;
  float* SI2  = w+o; o += (long)BB*NN;
  float* SJ2  = w+o; o += (long)BB*NN;
  float* KPART= w+o; o += (long)BB*NPB;
  float* hN   = w+o; o += FF;
  float* sN   = w+o; o += 2;
  float* DECP = w+o; o += (long)BB*16*(FF+1);
  float* keyG = w+o; o += (long)BB*NN;
  float* SBG  = w+o; o += (long)BB*NN;
  float* SDG  = w+o; o += (long)BB*NN;
  int* act = (int*)(w+o); o += (long)BB*NN;
  int* pjG = (int*)(w+o); o += (long)BB*NN;
  int* cnt = (int*)(w+o); o += BB;
  (void)in_sizes; (void)n_in; (void)out_size; (void)ws_size;

  // encoder layer 1 (shared h/si/sj across samples)
  k_rowmm<<<dim3(NN/8,1),128,0,stream>>>(embed, 0L,
      encW, encAs, encAd, H1, SI1, SJ1, nullptr);
  k_sortpre<<<BB+1,1024,0,stream>>>(data, embed, decW, decAs, decAd,
      SJ1, 0L, act, cnt, hN, sN, keyG, pjG, SBG, SDG);
  k_chunk <<<dim3(NCH,BB),128,0,stream>>>(keyG, pjG, cnt, H1, 0L, PP, PM);
  k_aggout<<<dim3(NN/TI,BB),128,0,stream>>>(keyG, SBG, SDG, PP, PM,
      SI1, 0L, act, cnt, XC);
  // encoder layer 2 (per-sample, compacted)
  k_rowmm<<<dim3(NN/8,BB),128,0,stream>>>(XC, (long)NN*FF,
      encW + FF*FF, encAs + FF, encAd + FF, H2, SI2, SJ2, cnt);
  k_sortpre<<<BB,1024,0,stream>>>(nullptr, embed, decW, decAs, decAd,
      SJ2, (long)NN, act, cnt, hN, sN, keyG, pjG, SBG, SDG);
  k_chunk <<<dim3(NCH,BB),128,0,stream>>>(keyG, pjG, cnt, H2, (long)NN*FF, PP, PM);
  k_aggout<<<dim3(NN/TI,BB),128,0,stream>>>(keyG, SBG, SDG, PP, PM,
      SI2, (long)NN, nullptr, cnt, XC);
  // param head + kld partials (XC -> MEAN into H2)
  k_par<<<dim3(NPB,BB),256,0,stream>>>(XC, pW, pB, H2 /*MEAN*/, KPART, cnt);
  // decoder projection + scores (MEAN=H2 -> H3=XC)
  k_rowmm<<<dim3(NN/8,BB),128,0,stream>>>(H2 /*MEAN*/, (long)NN*FF,
      decW, decAs, decAd, XC /*H3*/, SI2, SJ2, cnt);
  k_dec<<<dim3(16,BB),128,0,stream>>>(XC /*H3*/, SJ2, sN, cnt, DECP);
  k_head<<<BB+1,128,0,stream>>>(DECP, hN, sN, KPART, cnt, oW1, oB1, oW2, oB2, out);
}